// Round 5
// baseline (388.356 us; speedup 1.0000x reference)
//
#include <hip/hip_runtime.h>
#include <math.h>

// 10-qubit real-amplitude circuit simulator, batch 16384, depth 8.
// Layout: 8 lanes per batch element (index bits [2:0] = lane&7),
//         64 x float2 (=128 scalars) per lane; scalar bit0 = float2 component.
// Qubit q <-> scalar-index bit (9-q) for q0..q6 (bits 6..0);
// q7,q8,q9 <-> lane bits 2,1,0.
//
// Layer structure (gates reordered by verified commutations):
//   1. fused cross-lane CNOTs (6,7),(8,9),(7,8): ONE ds_bpermute per scalar
//   2. reg-reg CNOT swaps A..F in time order (pure register renames)
//   3. RY q0..q5 packed (v_pk_fma_f32), q6 in-pair, q7..q9 via ds_swizzle

typedef float v2f __attribute__((ext_vector_type(2)));

// ---- cross-lane helpers -------------------------------------------------
template<int CTRL>
__device__ __forceinline__ float dpp_mov(float x) {
  int i = __builtin_bit_cast(int, x);
  i = __builtin_amdgcn_update_dpp(i, i, CTRL, 0xf, 0xf, true);
  return __builtin_bit_cast(float, i);
}
__device__ __forceinline__ float xl1(float x) { return dpp_mov<0xB1>(x); }  // lane^1
__device__ __forceinline__ float xl2(float x) { return dpp_mov<0x4E>(x); }  // lane^2
template<int PAT>
__device__ __forceinline__ float swz(float x) {  // ds_swizzle BitMode
  int i = __builtin_amdgcn_ds_swizzle(__builtin_bit_cast(int, x), PAT);
  return __builtin_bit_cast(float, i);
}
__device__ __forceinline__ float xl4(float x) { return swz<0x101F>(x); }    // lane^4
__device__ __forceinline__ float bperm(int addr, float x) {
  int i = __builtin_amdgcn_ds_bpermute(addr, __builtin_bit_cast(int, x));
  return __builtin_bit_cast(float, i);
}
__device__ __forceinline__ float red8(float x) {
  x += xl1(x); x += xl2(x); x += xl4(x); return x;
}

// ---- RY on a register-bit qubit with pair stride Mw (packed) ------------
template<int Mw>
__device__ __forceinline__ void ry_w(v2f* w, v2f cc, v2f ss) {
  #pragma unroll
  for (int u = 0; u < 64; ++u) {
    if ((u & Mw) == 0) {
      v2f a = w[u], b = w[u + Mw];
      w[u]      = cc * a - ss * b;
      w[u + Mw] = ss * a + cc * b;
    }
  }
}

// ---- one level of the sum/diff tree -------------------------------------
template<int L2>
__device__ __forceinline__ float tree_level(float* t) {
  float a = 0.f, b = 0.f;
  #pragma unroll
  for (int j = 0; j < L2; ++j) {
    float e = t[2 * j], o = t[2 * j + 1];
    if (j & 1) b += e - o; else a += e - o;
    t[j] = e + o;
  }
  return a + b;
}

__global__ __launch_bounds__(256) void circuit_kernel(
    const float* __restrict__ x, const float* __restrict__ params,
    float* __restrict__ out) {
  __shared__ float stage[4][8][392];
  __shared__ float csh[160];  // cos/sin of pi*tanh(param)/2, [l*20 + 2q {+1}]

  const int tid  = threadIdx.x;
  const int wv   = tid >> 6;
  const int lane = tid & 63;
  const int g    = lane >> 3;
  const int l3   = lane & 7;
  const long elemBase = (long)blockIdx.x * 32 + (long)wv * 8;
  const long elem     = elemBase + g;

  if (tid < 80) {
    float th = 1.57079632679489662f * tanhf(params[tid]);  // (pi*tanh)/2
    csh[2 * tid]     = cosf(th);
    csh[2 * tid + 1] = sinf(th);
  }

  // bpermute source addresses for the fused cross-lane CNOT block
  // (pull map = inverse of push (7,8)o(8,9)[o xor4 for odd scalars]):
  const int mE = (l3 & 4) ? (l3 ^ 2) : l3;
  const int sE = (mE & 2) ? (mE ^ 1) : mE;
  const int addrE = ((lane & ~7) | sE) << 2;
  const int addrO = addrE ^ 16;

  v2f w[64];

  // ---- load 784 cols via coalesced float4 -> LDS -> registers ------------
  #pragma unroll
  for (int h = 0; h < 2; ++h) {
    #pragma unroll
    for (int t = 0; t < 13; ++t) {
      int f = t * 64 + lane;
      if (f < 784) {
        int row = f / 98;
        int c4  = f - row * 98;
        float4 val = reinterpret_cast<const float4*>(
            x + (elemBase + row) * 784 + h * 392)[c4];
        reinterpret_cast<float4*>(&stage[wv][row][0])[c4] = val;
      }
    }
    __syncthreads();
    #pragma unroll
    for (int k = 0; k < 49; ++k) {
      float val = stage[wv][g][k * 8 + l3];
      int r = h * 49 + k;
      if (r & 1) w[r >> 1].y = val; else w[r >> 1].x = val;
    }
    __syncthreads();
  }
  #pragma unroll
  for (int u = 49; u < 64; ++u) w[u] = (v2f){0.f, 0.f};

  // ---- L2 normalize ------------------------------------------------------
  v2f acc2 = {0.f, 0.f};
  #pragma unroll
  for (int u = 0; u < 49; ++u) acc2 += w[u] * w[u];
  float nn = red8(acc2.x + acc2.y);
  float scl = 1.0f / sqrtf(nn);
  v2f scl2 = {scl, scl};
  #pragma unroll
  for (int u = 0; u < 49; ++u) w[u] *= scl2;

  // ---- 8 layers ----------------------------------------------------------
  #pragma unroll 1
  for (int l = 0; l < 8; ++l) {
    const float* cl = &csh[l * 20];

    // 1. fused cross-lane CNOTs (6,7),(8,9),(7,8): one bpermute per scalar
    #pragma unroll
    for (int u = 0; u < 64; ++u) {
      w[u].x = bperm(addrE, w[u].x);
      w[u].y = bperm(addrO, w[u].y);
    }

    // 2. reg-reg CNOT swaps, time order A,B,C,D,E,F (scalar bit0 = component)
    // A (b6->b5): ctrl u&32, tgt u&16
    #pragma unroll
    for (int u = 32; u < 48; ++u) { v2f t = w[u]; w[u] = w[u + 16]; w[u + 16] = t; }
    // B (b4->b3): ctrl u&8, tgt u&4
    #pragma unroll
    for (int u = 0; u < 64; ++u) if ((u & 12) == 8) { v2f t = w[u]; w[u] = w[u + 4]; w[u + 4] = t; }
    // C (b2->b1): ctrl u&2, tgt u&1
    #pragma unroll
    for (int u = 0; u < 64; ++u) if ((u & 3) == 2) { v2f t = w[u]; w[u] = w[u + 1]; w[u + 1] = t; }
    // D (b5->b4): ctrl u&16, tgt u&8
    #pragma unroll
    for (int u = 0; u < 64; ++u) if ((u & 24) == 16) { v2f t = w[u]; w[u] = w[u + 8]; w[u + 8] = t; }
    // E (b3->b2): ctrl u&4, tgt u&2
    #pragma unroll
    for (int u = 0; u < 64; ++u) if ((u & 6) == 4) { v2f t = w[u]; w[u] = w[u + 2]; w[u + 2] = t; }
    // F (b1->b0): ctrl u&1, tgt = component -> in-register x<->y swap
    #pragma unroll
    for (int u = 1; u < 64; u += 2) w[u] = __builtin_shufflevector(w[u], w[u], 1, 0);

    // 3. RY q0..q5 (packed)
    { v2f cc = {cl[0],  cl[0]},  ss = {cl[1],  cl[1]};  ry_w<32>(w, cc, ss); }
    { v2f cc = {cl[2],  cl[2]},  ss = {cl[3],  cl[3]};  ry_w<16>(w, cc, ss); }
    { v2f cc = {cl[4],  cl[4]},  ss = {cl[5],  cl[5]};  ry_w< 8>(w, cc, ss); }
    { v2f cc = {cl[6],  cl[6]},  ss = {cl[7],  cl[7]};  ry_w< 4>(w, cc, ss); }
    { v2f cc = {cl[8],  cl[8]},  ss = {cl[9],  cl[9]};  ry_w< 2>(w, cc, ss); }
    { v2f cc = {cl[10], cl[10]}, ss = {cl[11], cl[11]}; ry_w< 1>(w, cc, ss); }

    // RY q6 (within-float2): w' = (c,s)*w.xx + (-s,c)*w.yy
    {
      v2f A = {cl[12], cl[13]};
      v2f B = {-cl[13], cl[12]};
      #pragma unroll
      for (int u = 0; u < 64; ++u) {
        v2f lo = {w[u].x, w[u].x};
        v2f hi = {w[u].y, w[u].y};
        w[u] = A * lo + B * hi;
      }
    }

    // RY q7/q8/q9 (lane bits 2/1/0): partner via ds_swizzle (DS pipe)
    {
      float c = cl[14], s = cl[15];
      float sn = (lane & 4) ? s : -s;
      v2f cc = {c, c}, ss2 = {sn, sn};
      #pragma unroll
      for (int u = 0; u < 64; ++u) {
        v2f p = { swz<0x101F>(w[u].x), swz<0x101F>(w[u].y) };
        w[u] = cc * w[u] + ss2 * p;
      }
    }
    {
      float c = cl[16], s = cl[17];
      float sn = (lane & 2) ? s : -s;
      v2f cc = {c, c}, ss2 = {sn, sn};
      #pragma unroll
      for (int u = 0; u < 64; ++u) {
        v2f p = { swz<0x081F>(w[u].x), swz<0x081F>(w[u].y) };
        w[u] = cc * w[u] + ss2 * p;
      }
    }
    {
      float c = cl[18], s = cl[19];
      float sn = (lane & 1) ? s : -s;
      v2f cc = {c, c}, ss2 = {sn, sn};
      #pragma unroll
      for (int u = 0; u < 64; ++u) {
        v2f p = { swz<0x041F>(w[u].x), swz<0x041F>(w[u].y) };
        w[u] = cc * w[u] + ss2 * p;
      }
    }
  }

  // ---- expectation values ------------------------------------------------
  #pragma unroll
  for (int u = 0; u < 64; ++u) w[u] *= w[u];   // probabilities

  float t[64];
  float a0 = 0.f, a1 = 0.f;
  #pragma unroll
  for (int u = 0; u < 64; ++u) {
    float d = w[u].x - w[u].y;
    if (u & 1) a1 += d; else a0 += d;
    t[u] = w[u].x + w[u].y;
  }
  float z[10];
  z[6] = red8(a0 + a1);
  z[5] = red8(tree_level<32>(t));
  z[4] = red8(tree_level<16>(t));
  z[3] = red8(tree_level< 8>(t));
  z[2] = red8(tree_level< 4>(t));
  z[1] = red8(tree_level< 2>(t));
  z[0] = red8(tree_level< 1>(t));
  float W = t[0];  // per-lane total probability
  { float u2 = W + xl1(W); u2 += xl2(u2); float tt = u2 - xl4(u2); z[7] = (lane & 4) ? -tt : tt; }
  { float u2 = W + xl1(W); float tt = u2 - xl2(u2); tt += xl4(tt); z[8] = (lane & 2) ? -tt : tt; }
  { float tt = W - xl1(W); tt += xl2(tt); tt += xl4(tt);           z[9] = (lane & 1) ? -tt : tt; }

  // ---- store -------------------------------------------------------------
  float o1 = z[0];
  #pragma unroll
  for (int j = 1; j < 8; ++j) o1 = (l3 == j) ? z[j] : o1;
  out[elem * 10 + l3] = o1;
  if (l3 < 2) out[elem * 10 + 8 + l3] = (l3 == 0) ? z[8] : z[9];
}

extern "C" void kernel_launch(void* const* d_in, const int* in_sizes, int n_in,
                              void* d_out, int out_size, void* d_ws, size_t ws_size,
                              hipStream_t stream) {
  const float* x      = (const float*)d_in[0];   // [16384, 784]
  const float* params = (const float*)d_in[1];   // [8, 10]
  float* out          = (float*)d_out;           // [16384, 10]
  (void)d_ws; (void)ws_size; (void)in_sizes; (void)n_in; (void)out_size;
  circuit_kernel<<<512, 256, 0, stream>>>(x, params, out);
}

// Round 6
// 92.647 us; speedup vs baseline: 4.1918x; 4.1918x over previous
//
#include <hip/hip_runtime.h>
#include <math.h>

// 10-qubit real-amplitude circuit simulator, batch 16384, depth 8.
// Layout (same as the verified 103us round-2 kernel):
//   8 lanes per batch element (index bits [2:0] = lane&7),
//   128 scalar float VGPRs per lane (index bits [9:3] = register index).
// Qubit q <-> index bit (9-q): q0..q6 -> r bits 6..0 ; q7,q8,q9 -> lane 2,1,0.
//
// Change vs round 2 (single variable): the three cross-lane CNOTs
// (6,7),(8,9),(7,8) are fused into ONE ds_bpermute per scalar
// (even r: addrE; odd r: addrE^16), removing ~512 VALU/layer of
// DPP+cndmask. Everything else is identical to round 2.

// ---- cross-lane helpers -------------------------------------------------
template<int CTRL>
__device__ __forceinline__ float dpp_mov(float x) {
  int i = __builtin_bit_cast(int, x);
  i = __builtin_amdgcn_update_dpp(i, i, CTRL, 0xf, 0xf, true);
  return __builtin_bit_cast(float, i);
}
__device__ __forceinline__ float xl1(float x) { return dpp_mov<0xB1>(x); }  // lane^1
__device__ __forceinline__ float xl2(float x) { return dpp_mov<0x4E>(x); }  // lane^2
__device__ __forceinline__ float xl4(float x) {                              // lane^4 (DS)
  int i = __builtin_amdgcn_ds_swizzle(__builtin_bit_cast(int, x), 0x101F);
  return __builtin_bit_cast(float, i);
}
__device__ __forceinline__ float bperm(int addr, float x) {
  int i = __builtin_amdgcn_ds_bpermute(addr, __builtin_bit_cast(int, x));
  return __builtin_bit_cast(float, i);
}
__device__ __forceinline__ float red8(float x) {
  x += xl1(x); x += xl2(x); x += xl4(x); return x;
}

// ---- RY on a register-bit qubit: pairs (r, r|M) -------------------------
template<int M>
__device__ __forceinline__ void ry_reg(float* v, float c, float s) {
  #pragma unroll
  for (int r = 0; r < 128; ++r) {
    if ((r & M) == 0) {
      float s0 = v[r], s1 = v[r + M];
      v[r]     = fmaf(c, s0, -(s * s1));
      v[r + M] = fmaf(s, s0,  c * s1);
    }
  }
}

// ---- RY on a lane-bit qubit: partner via xor-shuffle --------------------
template<int LM>
__device__ __forceinline__ void ry_lane(float* v, float c, float ss) {
  #pragma unroll
  for (int r = 0; r < 128; ++r) {
    float p = (LM == 4) ? xl4(v[r]) : (LM == 2) ? xl2(v[r]) : xl1(v[r]);
    v[r] = fmaf(c, v[r], ss * p);
  }
}

// ---- one level of the sum/diff tree -------------------------------------
template<int L2>
__device__ __forceinline__ float tree_level(float* v) {
  float a = 0.f, b = 0.f;
  #pragma unroll
  for (int j = 0; j < L2; ++j) {
    float e = v[2 * j], o = v[2 * j + 1];
    if (j & 1) b += e - o; else a += e - o;
    v[j] = e + o;
  }
  return a + b;
}

__global__ __launch_bounds__(256) void circuit_kernel(
    const float* __restrict__ x, const float* __restrict__ params,
    float* __restrict__ out) {
  __shared__ float stage[4][8][392];
  __shared__ float csh[160];  // cos/sin of pi*tanh(param)/2, [l*20 + 2q {+1}]

  const int tid  = threadIdx.x;
  const int wv   = tid >> 6;
  const int lane = tid & 63;
  const int g    = lane >> 3;
  const int l3   = lane & 7;
  const long elemBase = (long)blockIdx.x * 32 + (long)wv * 8;
  const long elem     = elemBase + g;

  if (tid < 80) {
    float th = 1.57079632679489662f * tanhf(params[tid]);  // (pi*tanh)/2
    csh[2 * tid]     = cosf(th);
    csh[2 * tid + 1] = sinf(th);
  }

  // bpermute pull-map for the fused cross-lane CNOT block:
  //   inverse of push [(6,7) if r odd] -> (8,9) -> (7,8)
  const int mE = (l3 & 4) ? (l3 ^ 2) : l3;   // undo (7,8)
  const int sE = (mE & 2) ? (mE ^ 1) : mE;   // undo (8,9)
  const int addrE = ((lane & ~7) | sE) << 2; // even r source (byte addr)
  const int addrO = addrE ^ 16;              // odd r: additionally lane^4

  float v[128];

  // ---- load 784 cols via coalesced float4 -> LDS -> registers ------------
  #pragma unroll
  for (int h = 0; h < 2; ++h) {
    #pragma unroll
    for (int t = 0; t < 13; ++t) {
      int f = t * 64 + lane;            // float4 index within 8x392 chunk
      if (f < 784) {
        int row = f / 98;
        int c4  = f - row * 98;
        float4 val = reinterpret_cast<const float4*>(
            x + (elemBase + row) * 784 + h * 392)[c4];
        reinterpret_cast<float4*>(&stage[wv][row][0])[c4] = val;
      }
    }
    __syncthreads();
    #pragma unroll
    for (int k = 0; k < 49; ++k)
      v[h * 49 + k] = stage[wv][g][k * 8 + l3];
    __syncthreads();
  }
  #pragma unroll
  for (int r = 98; r < 128; ++r) v[r] = 0.f;   // pad 784 -> 1024

  // ---- L2 normalize ------------------------------------------------------
  float nn = 0.f;
  #pragma unroll
  for (int r = 0; r < 98; ++r) nn = fmaf(v[r], v[r], nn);
  nn = red8(nn);
  float scl = 1.0f / sqrtf(nn);
  #pragma unroll
  for (int r = 0; r < 98; ++r) v[r] *= scl;

  // ---- 8 layers ----------------------------------------------------------
  #pragma unroll 1
  for (int l = 0; l < 8; ++l) {
    // 1. fused cross-lane CNOTs (6,7),(8,9),(7,8): one bpermute per scalar
    #pragma unroll
    for (int r = 0; r < 128; r += 2) {
      v[r]     = bperm(addrE, v[r]);
      v[r + 1] = bperm(addrO, v[r + 1]);
    }

    // 2. reg-reg CNOT swaps (pure renames), time order A,B,C,D,E,F
    // A (0,1): ctrl r6, tgt r5
    #pragma unroll
    for (int r = 64; r < 96; ++r) { float t = v[r]; v[r] = v[r + 32]; v[r + 32] = t; }
    // B (2,3): ctrl r4, tgt r3
    #pragma unroll
    for (int r = 0; r < 128; ++r) if ((r & 24) == 16) { float t = v[r]; v[r] = v[r + 8]; v[r + 8] = t; }
    // C (4,5): ctrl r2, tgt r1
    #pragma unroll
    for (int r = 0; r < 128; ++r) if ((r & 6) == 4) { float t = v[r]; v[r] = v[r + 2]; v[r + 2] = t; }
    // D (1,2): ctrl r5, tgt r4
    #pragma unroll
    for (int r = 0; r < 128; ++r) if ((r & 48) == 32) { float t = v[r]; v[r] = v[r + 16]; v[r + 16] = t; }
    // E (3,4): ctrl r3, tgt r2
    #pragma unroll
    for (int r = 0; r < 128; ++r) if ((r & 12) == 8) { float t = v[r]; v[r] = v[r + 4]; v[r + 4] = t; }
    // F (5,6): ctrl r1, tgt r0
    #pragma unroll
    for (int r = 0; r < 128; ++r) if ((r & 3) == 2) { float t = v[r]; v[r] = v[r + 1]; v[r + 1] = t; }

    // 3. RY gates q0..q9
    const float* cl = &csh[l * 20];
    ry_reg<64>(v, cl[0],  cl[1]);    // q0
    ry_reg<32>(v, cl[2],  cl[3]);    // q1
    ry_reg<16>(v, cl[4],  cl[5]);    // q2
    ry_reg< 8>(v, cl[6],  cl[7]);    // q3
    ry_reg< 4>(v, cl[8],  cl[9]);    // q4
    ry_reg< 2>(v, cl[10], cl[11]);   // q5
    ry_reg< 1>(v, cl[12], cl[13]);   // q6
    { float s = cl[15]; float ss = (lane & 4) ? s : -s; ry_lane<4>(v, cl[14], ss); } // q7
    { float s = cl[17]; float ss = (lane & 2) ? s : -s; ry_lane<2>(v, cl[16], ss); } // q8
    { float s = cl[19]; float ss = (lane & 1) ? s : -s; ry_lane<1>(v, cl[18], ss); } // q9
  }

  // ---- expectation values ------------------------------------------------
  float z[10];
  #pragma unroll
  for (int r = 0; r < 128; ++r) v[r] *= v[r];   // probabilities
  z[6] = red8(tree_level<64>(v));
  z[5] = red8(tree_level<32>(v));
  z[4] = red8(tree_level<16>(v));
  z[3] = red8(tree_level< 8>(v));
  z[2] = red8(tree_level< 4>(v));
  z[1] = red8(tree_level< 2>(v));
  z[0] = red8(tree_level< 1>(v));
  float W = v[0];  // per-lane total probability
  { float u = W + xl1(W); u += xl2(u); float t = u - xl4(u); z[7] = (lane & 4) ? -t : t; }
  { float u = W + xl1(W); float t = u - xl2(u); t += xl4(t); z[8] = (lane & 2) ? -t : t; }
  { float t = W - xl1(W); t += xl2(t); t += xl4(t);          z[9] = (lane & 1) ? -t : t; }

  // ---- store -------------------------------------------------------------
  float o1 = z[0];
  #pragma unroll
  for (int j = 1; j < 8; ++j) o1 = (l3 == j) ? z[j] : o1;
  out[elem * 10 + l3] = o1;
  if (l3 < 2) out[elem * 10 + 8 + l3] = (l3 == 0) ? z[8] : z[9];
}

extern "C" void kernel_launch(void* const* d_in, const int* in_sizes, int n_in,
                              void* d_out, int out_size, void* d_ws, size_t ws_size,
                              hipStream_t stream) {
  const float* x      = (const float*)d_in[0];   // [16384, 784]
  const float* params = (const float*)d_in[1];   // [8, 10]
  float* out          = (float*)d_out;           // [16384, 10]
  (void)d_ws; (void)ws_size; (void)in_sizes; (void)n_in; (void)out_size;
  circuit_kernel<<<512, 256, 0, stream>>>(x, params, out);
}

// Round 7
// 82.957 us; speedup vs baseline: 4.6814x; 1.1168x over previous
//
#include <hip/hip_runtime.h>
#include <math.h>

// 10-qubit real-amplitude circuit simulator, batch 16384, depth 8.
// Layout: 16 lanes per batch element (index bits [3:0] = lane&15),
//         64 scalar float VGPRs per lane (index bits [9:4] = register index).
// Qubit q <-> index bit (9-q): q0..q5 -> r bits 5..0 ; q6..q9 -> lane 3,2,1,0.
//
// Per layer:
//  1. reg-reg CNOT swaps (0,1),(2,3),(4,5),(1,2),(3,4) — pure renames
//  2. fused cross-lane CNOTs (6,7),(8,9),(5,6),(7,8) — ONE ds_bpermute per
//     scalar; (5,6) control = r&1 (post-swap) -> odd-r addr = addrE ^ 48
//  3. RY q0..q5 in-register; q6 via DPP row_ror:8 (lane^8 within 16-row);
//     q7 via ds_swizzle xor4; q8/q9 via DPP quad_perm (lane^2 / lane^1)

// ---- cross-lane helpers -------------------------------------------------
template<int CTRL>
__device__ __forceinline__ float dpp_mov(float x) {
  int i = __builtin_bit_cast(int, x);
  i = __builtin_amdgcn_update_dpp(i, i, CTRL, 0xf, 0xf, true);
  return __builtin_bit_cast(float, i);
}
__device__ __forceinline__ float xl1(float x) { return dpp_mov<0xB1>(x); }   // lane^1
__device__ __forceinline__ float xl2(float x) { return dpp_mov<0x4E>(x); }   // lane^2
__device__ __forceinline__ float xl8(float x) { return dpp_mov<0x128>(x); }  // row_ror:8 == lane^8 in 16-row
__device__ __forceinline__ float xl4(float x) {                               // lane^4 (DS)
  int i = __builtin_amdgcn_ds_swizzle(__builtin_bit_cast(int, x), 0x101F);
  return __builtin_bit_cast(float, i);
}
__device__ __forceinline__ float bperm(int addr, float x) {
  int i = __builtin_amdgcn_ds_bpermute(addr, __builtin_bit_cast(int, x));
  return __builtin_bit_cast(float, i);
}
__device__ __forceinline__ float red16(float x) {
  x += xl1(x); x += xl2(x); x += xl4(x); x += xl8(x); return x;
}

// ---- RY on a register-bit qubit: pairs (r, r|M) -------------------------
template<int M>
__device__ __forceinline__ void ry_reg(float* v, float c, float s) {
  #pragma unroll
  for (int r = 0; r < 64; ++r) {
    if ((r & M) == 0) {
      float s0 = v[r], s1 = v[r + M];
      v[r]     = fmaf(c, s0, -(s * s1));
      v[r + M] = fmaf(s, s0,  c * s1);
    }
  }
}

// ---- one level of the sum/diff tree -------------------------------------
template<int L2>
__device__ __forceinline__ float tree_level(float* v) {
  float a = 0.f, b = 0.f;
  #pragma unroll
  for (int j = 0; j < L2; ++j) {
    float e = v[2 * j], o = v[2 * j + 1];
    if (j & 1) b += e - o; else a += e - o;
    v[j] = e + o;
  }
  return a + b;
}

__global__ __launch_bounds__(256, 4) void circuit_kernel(
    const float* __restrict__ x, const float* __restrict__ params,
    float* __restrict__ out) {
  __shared__ float csh[160];  // cos/sin of pi*tanh(param)/2, [l*20 + 2q {+1}]

  const int tid  = threadIdx.x;
  const int wv   = tid >> 6;
  const int lane = tid & 63;
  const int g    = lane >> 4;   // element group within wave (0..3)
  const int l4   = lane & 15;   // lane within group = index bits [3:0]
  const long elem = (long)blockIdx.x * 16 + wv * 4 + g;

  if (tid < 80) {
    float th = 1.57079632679489662f * tanhf(params[tid]);  // (pi*tanh)/2
    csh[2 * tid]     = cosf(th);
    csh[2 * tid + 1] = sinf(th);
  }

  // bpermute pull map: m=l4; b1^=b2; [b3^=c]; b0^=b1; b2^=b3
  int m = l4 ^ ((l4 & 4) >> 1);     // b1 ^= b2
  m ^= (m & 2) >> 1;                // b0 ^= b1
  m ^= (m & 8) >> 1;                // b2 ^= b3
  const int addrE = ((lane & 48) | m) << 2;  // even-r source (byte addr)
  const int addrO = addrE ^ 48;              // odd r: c=1 flips b3 and b2

  // ---- load 49 stride-16 scalars (784 = 49*16), pad to 64 ---------------
  float v[64];
  const float* xb = x + elem * 784 + l4;
  #pragma unroll
  for (int k = 0; k < 49; ++k) v[k] = xb[k * 16];
  #pragma unroll
  for (int k = 49; k < 64; ++k) v[k] = 0.f;

  // ---- L2 normalize ------------------------------------------------------
  float nn = 0.f;
  #pragma unroll
  for (int k = 0; k < 49; ++k) nn = fmaf(v[k], v[k], nn);
  nn = red16(nn);
  float scl = 1.0f / sqrtf(nn);
  #pragma unroll
  for (int k = 0; k < 49; ++k) v[k] *= scl;

  __syncthreads();   // csh ready

  // ---- 8 layers ----------------------------------------------------------
  #pragma unroll 1
  for (int l = 0; l < 8; ++l) {
    // 1. reg-reg CNOT swaps (renames), time order (0,1),(2,3),(4,5),(1,2),(3,4)
    #pragma unroll
    for (int r = 32; r < 48; ++r) { float t = v[r]; v[r] = v[r + 16]; v[r + 16] = t; } // (0,1)
    #pragma unroll
    for (int r = 0; r < 64; ++r) if ((r & 12) == 8) { float t = v[r]; v[r] = v[r + 4]; v[r + 4] = t; } // (2,3)
    #pragma unroll
    for (int r = 0; r < 64; ++r) if ((r & 3) == 2) { float t = v[r]; v[r] = v[r + 1]; v[r + 1] = t; }  // (4,5)
    #pragma unroll
    for (int r = 0; r < 64; ++r) if ((r & 24) == 16) { float t = v[r]; v[r] = v[r + 8]; v[r + 8] = t; } // (1,2)
    #pragma unroll
    for (int r = 0; r < 64; ++r) if ((r & 6) == 4) { float t = v[r]; v[r] = v[r + 2]; v[r + 2] = t; }   // (3,4)

    // 2. fused cross-lane CNOTs (6,7),(8,9),(5,6),(7,8): one bpermute/scalar
    #pragma unroll
    for (int r = 0; r < 64; r += 2) {
      v[r]     = bperm(addrE, v[r]);
      v[r + 1] = bperm(addrO, v[r + 1]);
    }

    // 3. RY gates
    const float* cl = &csh[l * 20];
    ry_reg<32>(v, cl[0],  cl[1]);    // q0
    ry_reg<16>(v, cl[2],  cl[3]);    // q1
    ry_reg< 8>(v, cl[4],  cl[5]);    // q2
    ry_reg< 4>(v, cl[6],  cl[7]);    // q3
    ry_reg< 2>(v, cl[8],  cl[9]);    // q4
    ry_reg< 1>(v, cl[10], cl[11]);   // q5
    // q6 (lane bit 3) via DPP row_ror:8
    {
      float c = cl[12], s = cl[13];
      float sn = (lane & 8) ? s : -s;
      #pragma unroll
      for (int r = 0; r < 64; ++r) { float p = xl8(v[r]); v[r] = fmaf(c, v[r], sn * p); }
    }
    // q7 (lane bit 2) via ds_swizzle xor4
    {
      float c = cl[14], s = cl[15];
      float sn = (lane & 4) ? s : -s;
      #pragma unroll
      for (int r = 0; r < 64; ++r) { float p = xl4(v[r]); v[r] = fmaf(c, v[r], sn * p); }
    }
    // q8 (lane bit 1) via DPP xor2
    {
      float c = cl[16], s = cl[17];
      float sn = (lane & 2) ? s : -s;
      #pragma unroll
      for (int r = 0; r < 64; ++r) { float p = xl2(v[r]); v[r] = fmaf(c, v[r], sn * p); }
    }
    // q9 (lane bit 0) via DPP xor1
    {
      float c = cl[18], s = cl[19];
      float sn = (lane & 1) ? s : -s;
      #pragma unroll
      for (int r = 0; r < 64; ++r) { float p = xl1(v[r]); v[r] = fmaf(c, v[r], sn * p); }
    }
  }

  // ---- expectation values ------------------------------------------------
  float z[10];
  #pragma unroll
  for (int r = 0; r < 64; ++r) v[r] *= v[r];   // probabilities
  z[5] = red16(tree_level<32>(v));
  z[4] = red16(tree_level<16>(v));
  z[3] = red16(tree_level< 8>(v));
  z[2] = red16(tree_level< 4>(v));
  z[1] = red16(tree_level< 2>(v));
  z[0] = red16(tree_level< 1>(v));
  float W = v[0];  // per-lane total probability
  // lane-bit qubits: signed reductions over the 16-lane group
  { float u = W + xl1(W); u += xl2(u); u += xl4(u); float t = u - xl8(u); z[6] = (lane & 8) ? -t : t; }
  { float u = W + xl1(W); u += xl2(u); u += xl8(u); float t = u - xl4(u); z[7] = (lane & 4) ? -t : t; }
  { float u = W + xl1(W); u += xl4(u); u += xl8(u); float t = u - xl2(u); z[8] = (lane & 2) ? -t : t; }
  { float u = W + xl2(W); u += xl4(u); u += xl8(u); float t = u - xl1(u); z[9] = (lane & 1) ? -t : t; }

  // ---- store: lane l4 (<10) writes column l4 -----------------------------
  float o = z[0];
  #pragma unroll
  for (int j = 1; j < 10; ++j) o = (l4 == j) ? z[j] : o;
  if (l4 < 10) out[elem * 10 + l4] = o;
}

extern "C" void kernel_launch(void* const* d_in, const int* in_sizes, int n_in,
                              void* d_out, int out_size, void* d_ws, size_t ws_size,
                              hipStream_t stream) {
  const float* x      = (const float*)d_in[0];   // [16384, 784]
  const float* params = (const float*)d_in[1];   // [8, 10]
  float* out          = (float*)d_out;           // [16384, 10]
  (void)d_ws; (void)ws_size; (void)in_sizes; (void)n_in; (void)out_size;
  // 16384 elements / 16 per block (4 per wave x 4 waves)
  circuit_kernel<<<1024, 256, 0, stream>>>(x, params, out);
}